// Round 17
// baseline (101.399 us; speedup 1.0000x reference)
//
#include <hip/hip_runtime.h>

#define BATCH 4
#define SEQ   2048
#define EMB   128
#define NH    16
#define DK    8

// log2(e) / sqrt(8): fold softmax temperature into exp2 (pre-multiplied into qf)
#define QSCALE 0.510069726f

typedef _Float16 v4h  __attribute__((ext_vector_type(4)));
typedef _Float16 v8h  __attribute__((ext_vector_type(8)));
typedef __fp16   v2fp __attribute__((ext_vector_type(2)));
typedef float    v4f  __attribute__((ext_vector_type(4)));
typedef float    v16f __attribute__((ext_vector_type(16)));

#define CHUNK  512
#define VTP    520    // VT col pitch (f16): 260 dwords %32 = 4 -> 2-way max

// ---------------------------------------------------------------------------
// Fused features + 32x32 MFMA attention, IN-BLOCK SPLIT-K.
// Block = 512 thr = 8 waves = 2 key-split groups x 4 waves. Group g owns
// keys [g*1024, (g+1)*1024) staged as 2 chunks of 512 into its OWN Kl/VT
// (LDS 36.5 KB total) -> grid 1024 gives 4 blocks/CU = 2048 thr/CU =
// 8 waves/SIMD — double R16's wave supply for the same per-wave exp demand
// (exp@8cyc is the issue-port hog; more waves fill the mfma->exp holes).
// Each wave owns 32 q-rows; both groups cover the same 128 q of the block.
// Partials (4 dims + den per lane-half) combine through group-1's dead Kl
// buffer at the end (stride-5 floats: conflict-free); NO reduce kernel, no
// global partial traffic (unlike R14's global split-K which regressed).
//
// Math (HW-verified layouts, R15/16-proven): S^T = mfma_32x32x16(A=K,B=Q^T);
// C/D: col=L&31, row=(reg&3)+8(reg>>2)+4(L>>5). P=exp2(S^T) packs via pkrtz
// in natural reg order into the PV B-frag PROVIDED V^T is stored with
// key-index bits 2<->3 swapped (consistent k-slot permutation). qf=0 on
// half1 kills k=8..15 padding. Ones-row d=8 of V^T gives the denominator;
// out rows 9..31 garbage (clamped VT row 9), never stored.
// Plain-exp softmax exact: |score*log2e/sqrt8| <= 4.1 (features <= 1);
// split combination is sum-order only.
// ---------------------------------------------------------------------------
__launch_bounds__(512, 8)
__global__ void attn_kernel(const float* __restrict__ x,
                            const float* __restrict__ theta,
                            _Float16* __restrict__ Ah /* [B*S][128] f16 */) {
  __shared__ __align__(16) _Float16 Kl[2][CHUNK * 8];   // 2 x 8 KB
  __shared__ __align__(16) _Float16 VT[2][10][VTP];     // 2 x 10.2 KB

  const int tid = threadIdx.x;
  const int L   = tid & 63;
  const int ln  = L & 31;
  const int hf  = L >> 5;           // lane half
  const int wv  = tid >> 6;         // wave 0..7
  const int sg  = wv >> 2;          // split group 0/1
  const int wl  = wv & 3;           // wave within group
  const int tg  = tid & 255;        // thread within group
  const int bh     = blockIdx.x >> 4;
  const int qchunk = blockIdx.x & 15;
  const int qb     = qchunk * 128 + wl * 32;   // wave's 32 q rows
  const int b = bh >> 4;
  const int h = bh & 15;

  float th[DK];
#pragma unroll
  for (int i = 0; i < DK; ++i) th[i] = theta[i];

  // own group's VT row 8 = ones (denominator), row 9 = 0 (clamp target)
  for (int i = tg; i < VTP; i += 256) {
    VT[sg][8][i] = (_Float16)1.0f;
    VT[sg][9][i] = (_Float16)0.0f;
  }

  const int mrow = (ln < 9) ? ln : 9;   // clamped VT row for PV A-frag
  const float* xb = x + (size_t)b * SEQ * EMB + h * DK;

  // ---- self-compute q fragment from x (half0 lanes; half1 stays 0) ----
  v8h qf = {0, 0, 0, 0, 0, 0, 0, 0};
  if (hf == 0) {
    const int qrow = qb + ln;
    const float* xq = x + ((size_t)b * SEQ + qrow) * EMB + h * DK;
    const float4 a0 = *(const float4*)(xq);
    const float4 a1 = *(const float4*)(xq + 4);
    float r[8];
    r[0] = __cosf(a0.x + th[0]);
    r[1] = r[0] * __cosf(a0.y + th[1]);
    r[2] = r[1] * __cosf(a0.z + th[2]);
    r[3] = r[2] * __cosf(a0.w + th[3]);
    r[4] = r[3] * __cosf(a1.x + th[4]);
    r[5] = r[4] * __cosf(a1.y + th[5]);
    r[6] = r[5] * __cosf(a1.z + th[6]);
    r[7] = r[6] * __cosf(a1.w + th[7]);
    qf = (v8h){(_Float16)(r[0] * QSCALE), (_Float16)(r[1] * QSCALE),
               (_Float16)(r[2] * QSCALE), (_Float16)(r[3] * QSCALE),
               (_Float16)(r[4] * QSCALE), (_Float16)(r[5] * QSCALE),
               (_Float16)(r[6] * QSCALE), (_Float16)(r[7] * QSCALE)};
  }

  // prefetch round-0 x rows (keys tg, tg+256 of this group's first chunk)
  const int cbase = sg * 2;
  float4 pa0, pa1, pb0, pb1;
  {
    const float* xp = xb + (size_t)(cbase * CHUNK + tg) * EMB;
    pa0 = *(const float4*)(xp);
    pa1 = *(const float4*)(xp + 4);
    pb0 = *(const float4*)(xp + 256 * EMB);
    pb1 = *(const float4*)(xp + 256 * EMB + 4);
  }

  v16f acc;
#pragma unroll
  for (int i = 0; i < 16; ++i) acc[i] = 0.f;
  v16f zf;
#pragma unroll
  for (int i = 0; i < 16; ++i) zf[i] = 0.f;

  for (int cg = 0; cg < 2; ++cg) {
    if (cg) __syncthreads();

    // ---- stage own group's chunk (16 B/lane Kl writes; VT slot-permuted) ----
    {
      float r0[8], r1[8];
      r0[0] = __cosf(pa0.x + th[0]);
      r0[1] = r0[0] * __cosf(pa0.y + th[1]);
      r0[2] = r0[1] * __cosf(pa0.z + th[2]);
      r0[3] = r0[2] * __cosf(pa0.w + th[3]);
      r0[4] = r0[3] * __cosf(pa1.x + th[4]);
      r0[5] = r0[4] * __cosf(pa1.y + th[5]);
      r0[6] = r0[5] * __cosf(pa1.z + th[6]);
      r0[7] = r0[6] * __cosf(pa1.w + th[7]);
      r1[0] = __cosf(pb0.x + th[0]);
      r1[1] = r1[0] * __cosf(pb0.y + th[1]);
      r1[2] = r1[1] * __cosf(pb0.z + th[2]);
      r1[3] = r1[2] * __cosf(pb0.w + th[3]);
      r1[4] = r1[3] * __cosf(pb1.x + th[4]);
      r1[5] = r1[4] * __cosf(pb1.y + th[5]);
      r1[6] = r1[5] * __cosf(pb1.z + th[6]);
      r1[7] = r1[6] * __cosf(pb1.w + th[7]);

      _Float16 h0[8], h1[8];
#pragma unroll
      for (int i = 0; i < 8; ++i) { h0[i] = (_Float16)r0[i]; h1[i] = (_Float16)r1[i]; }

      union { v4h v[2]; float4 f; } u0, u1;
      u0.v[0] = (v4h){h0[0], h0[1], h0[2], h0[3]};
      u0.v[1] = (v4h){h0[4], h0[5], h0[6], h0[7]};
      u1.v[0] = (v4h){h1[0], h1[1], h1[2], h1[3]};
      u1.v[1] = (v4h){h1[4], h1[5], h1[6], h1[7]};
      *(float4*)&Kl[sg][tg * 8]         = u0.f;
      *(float4*)&Kl[sg][(tg + 256) * 8] = u1.f;

      // VT with within-16 slot perm (swap bits 2<->3 of key index)
      const int j0 = tg, j1 = tg + 256;
      const int col0 = (j0 & ~15) | (j0 & 3) | ((j0 & 4) << 1) | ((j0 & 8) >> 1);
      const int col1 = (j1 & ~15) | (j1 & 3) | ((j1 & 4) << 1) | ((j1 & 8) >> 1);
#pragma unroll
      for (int d = 0; d < 8; ++d) {
        VT[sg][d][col0] = h0[d];
        VT[sg][d][col1] = h1[d];
      }
    }
    __syncthreads();

    // prefetch round-1 x rows (consumed after this compute phase)
    if (cg == 0) {
      const float* xp = xb + (size_t)((cbase + 1) * CHUNK + tg) * EMB;
      pa0 = *(const float4*)(xp);
      pa1 = *(const float4*)(xp + 4);
      pb0 = *(const float4*)(xp + 256 * EMB);
      pb1 = *(const float4*)(xp + 256 * EMB + 4);
    }

    // ---- compute: 16 32-key blocks, software-pipelined ----
    v8h kf_next = *(const v8h*)&Kl[sg][ln * 8];
#pragma unroll 2
    for (int kb = 0; kb < CHUNK / 32; ++kb) {
      const v8h kf = kf_next;
      const v16f s = __builtin_amdgcn_mfma_f32_32x32x16_f16(kf, qf, zf, 0, 0, 0);
      if (kb + 1 < CHUNK / 32)
        kf_next = *(const v8h*)&Kl[sg][((kb + 1) * 32 + ln) * 8];
      const v8h vt0 = *(const v8h*)&VT[sg][mrow][kb * 32 + hf * 8];
      const v8h vt1 = *(const v8h*)&VT[sg][mrow][kb * 32 + 16 + hf * 8];
      union { v2fp p[4]; v8h v; } p0, p1;
#pragma unroll
      for (int i = 0; i < 4; ++i) {
        p0.p[i] = __builtin_amdgcn_cvt_pkrtz(
            __builtin_amdgcn_exp2f(s[2 * i]),
            __builtin_amdgcn_exp2f(s[2 * i + 1]));
        p1.p[i] = __builtin_amdgcn_cvt_pkrtz(
            __builtin_amdgcn_exp2f(s[8 + 2 * i]),
            __builtin_amdgcn_exp2f(s[8 + 2 * i + 1]));
      }
      acc = __builtin_amdgcn_mfma_f32_32x32x16_f16(vt0, p0.v, acc, 0, 0, 0);
      acc = __builtin_amdgcn_mfma_f32_32x32x16_f16(vt1, p1.v, acc, 0, 0, 0);
    }
  }

  // ---- combine split groups through group-1's dead Kl buffer ----
  // acc: col=q=ln, half0 regs0-3 = dims0-3, reg4 = den; half1 regs0-3 =
  // dims4-7, reg4 = 0 (VT row 12 clamped to zeros row 9).
  __syncthreads();                       // everyone done reading Kl[1]
  float* part = (float*)&Kl[1][0];       // 2048 floats >= 4*2*32*5
  if (sg == 1) {
    float* p = part + (((wl * 2 + hf) * 32) + ln) * 5;
    p[0] = acc[0]; p[1] = acc[1]; p[2] = acc[2]; p[3] = acc[3]; p[4] = acc[4];
  }
  __syncthreads();
  if (sg == 0) {
    const float* p = part + (((wl * 2 + hf) * 32) + ln) * 5;
    acc[0] += p[0]; acc[1] += p[1]; acc[2] += p[2]; acc[3] += p[3];
    acc[4] += p[4];
    const float den = __shfl(acc[4], ln, 64);   // from half0 lane ln
    const float inv = 1.0f / den;
    const int qrow = qb + ln;
    v4h o = {(_Float16)(acc[0] * inv), (_Float16)(acc[1] * inv),
             (_Float16)(acc[2] * inv), (_Float16)(acc[3] * inv)};
    *(v4h*)(Ah + ((size_t)b * SEQ + qrow) * EMB + h * DK + hf * 4) = o;
  }
}

// ---------------------------------------------------------------------------
// MFMA projection (unchanged from R10-R16). out = Ah · W^T, fp32 out.
// W converted f32->f16 during LDS staging; W row-major IS the B-fragment
// source. Block: 64 rows x 64 cols (grid 128x2), LDS 35 KB, 4 blocks/CU.
// ---------------------------------------------------------------------------
__launch_bounds__(256, 4)
__global__ void proj_kernel(const _Float16* __restrict__ Ah,
                            const float* __restrict__ W,
                            float* __restrict__ out) {
  __shared__ __align__(16) _Float16 Ahs[64][136];
  __shared__ __align__(16) _Float16 Whs[64][136];

  const int tid  = threadIdx.x;
  const int L    = tid & 63;
  const int wv   = tid >> 6;
  const int quad = L >> 4;
  const int ln   = L & 15;
  const int rowbase = blockIdx.x * 64;
  const int colbase = blockIdx.y * 64;

#pragma unroll
  for (int it = 0; it < 4; ++it) {
    const int idx = it * 256 + tid;
    const int r  = idx >> 4;
    const int c8 = idx & 15;
    *(uint4*)&Ahs[r][c8 * 8] =
        *(const uint4*)(Ah + (size_t)(rowbase + r) * EMB + c8 * 8);
  }
#pragma unroll
  for (int it = 0; it < 8; ++it) {
    const int idx = it * 256 + tid;
    const int n  = idx >> 5;
    const int c4 = idx & 31;
    const float4 w = *(const float4*)(W + (size_t)(colbase + n) * EMB + c4 * 4);
    v4h wh = {(_Float16)w.x, (_Float16)w.y, (_Float16)w.z, (_Float16)w.w};
    *(v4h*)&Whs[n][c4 * 4] = wh;
  }
  __syncthreads();

  v4f acc[4];
#pragma unroll
  for (int nt = 0; nt < 4; ++nt) acc[nt] = (v4f){0.f, 0.f, 0.f, 0.f};

#pragma unroll
  for (int k8 = 0; k8 < 8; ++k8) {
    const v4h af = *(const v4h*)&Ahs[wv * 16 + ln][k8 * 16 + quad * 4];
#pragma unroll
    for (int nt = 0; nt < 4; ++nt) {
      const v4h bf = *(const v4h*)&Whs[nt * 16 + ln][k8 * 16 + quad * 4];
      acc[nt] = __builtin_amdgcn_mfma_f32_16x16x16f16(af, bf, acc[nt], 0, 0, 0);
    }
  }

#pragma unroll
  for (int nt = 0; nt < 4; ++nt) {
    const int col = colbase + nt * 16 + ln;
#pragma unroll
    for (int r = 0; r < 4; ++r) {
      out[(size_t)(rowbase + wv * 16 + quad * 4 + r) * EMB + col] = acc[nt][r];
    }
  }
}

// ---------------------------------------------------------------------------
extern "C" void kernel_launch(void* const* d_in, const int* in_sizes, int n_in,
                              void* d_out, int out_size, void* d_ws, size_t ws_size,
                              hipStream_t stream) {
  const float* x     = (const float*)d_in[0];  // [4,2048,128]
  const float* theta = (const float*)d_in[1];  // [8]
  const float* w_out = (const float*)d_in[2];  // [128,128]
  float* out = (float*)d_out;                  // [4,2048,128]

  _Float16* Ah = (_Float16*)d_ws;              // [8192][128] f16 = 2 MB

  // fused features + attention: 64 bh x 16 q-chunks = 1024 blocks, 8 waves
  attn_kernel<<<dim3(1024), dim3(512), 0, stream>>>(x, theta, Ah);

  // projection: 128 row-tiles x 2 col-tiles
  proj_kernel<<<dim3((BATCH * SEQ) / 64, 2), dim3(256), 0, stream>>>(Ah, w_out, out);
}

// Round 18
// 95.259 us; speedup vs baseline: 1.0645x; 1.0645x over previous
//
#include <hip/hip_runtime.h>

#define BATCH 4
#define SEQ   2048
#define EMB   128
#define NH    16
#define DK    8

// log2(e) / sqrt(8): fold softmax temperature into exp2 (pre-multiplied into qf)
#define QSCALE 0.510069726f

typedef _Float16 v4h  __attribute__((ext_vector_type(4)));
typedef _Float16 v8h  __attribute__((ext_vector_type(8)));
typedef __fp16   v2fp __attribute__((ext_vector_type(2)));
typedef float    v4f  __attribute__((ext_vector_type(4)));
typedef float    v16f __attribute__((ext_vector_type(16)));

#define CHUNK  512
#define VTP    520    // VT col pitch (f16): 260 dwords %32 = 4 -> 2-way max

// ---------------------------------------------------------------------------
// Fused features + 32x32 MFMA attention, IN-BLOCK SPLIT-K (R17 structure,
// SLIMMED to fit the 64-VGPR cap of 8 waves/SIMD — R17 spilled ~27 MB of
// scratch writes; this version drops the x-prefetch registers and the kf
// software pipeline, letting 32 waves/CU hide latency instead of registers).
//
// Block = 512 thr = 8 waves = 2 key-split groups x 4 waves. Group g owns
// keys [g*1024, (g+1)*1024) staged as 2 chunks of 512 into its OWN Kl/VT.
// LDS 36.5 KB -> 4 blocks/CU = 2048 thr/CU = 8 waves/SIMD. Each wave owns
// 32 q-rows. Partials combine through group-1's dead Kl buffer (stride-5
// floats, conflict-free); no reduce kernel, no global partial traffic.
//
// Math (HW-verified, R15-R17-proven): S^T = mfma_32x32x16(A=K, B=Q^T);
// C/D: col=L&31, row=(reg&3)+8(reg>>2)+4(L>>5). P=exp2(S^T) packs via pkrtz
// in natural reg order into the PV B-frag PROVIDED V^T is stored with
// key-index bits 2<->3 swapped (consistent k-slot permutation). qf=0 on
// half1 kills k=8..15 padding. Ones-row d=8 of V^T gives the denominator;
// out rows 9..31 garbage (clamped VT row 9), never stored.
// Plain-exp softmax exact: |score*log2e/sqrt8| <= 4.1 (features <= 1).
// ---------------------------------------------------------------------------
__launch_bounds__(512, 8)
__global__ void attn_kernel(const float* __restrict__ x,
                            const float* __restrict__ theta,
                            _Float16* __restrict__ Ah /* [B*S][128] f16 */) {
  __shared__ __align__(16) _Float16 Kl[2][CHUNK * 8];   // 2 x 8 KB
  __shared__ __align__(16) _Float16 VT[2][10][VTP];     // 2 x 10.2 KB

  const int tid = threadIdx.x;
  const int L   = tid & 63;
  const int ln  = L & 31;
  const int hf  = L >> 5;           // lane half
  const int wv  = tid >> 6;         // wave 0..7
  const int sg  = wv >> 2;          // split group 0/1
  const int wl  = wv & 3;           // wave within group
  const int tg  = tid & 255;        // thread within group
  const int bh     = blockIdx.x >> 4;
  const int qchunk = blockIdx.x & 15;
  const int qb     = qchunk * 128 + wl * 32;   // wave's 32 q rows
  const int b = bh >> 4;
  const int h = bh & 15;

  float th[DK];
#pragma unroll
  for (int i = 0; i < DK; ++i) th[i] = theta[i];   // uniform -> SGPRs

  // own group's VT row 8 = ones (denominator), row 9 = 0 (clamp target)
  for (int i = tg; i < VTP; i += 256) {
    VT[sg][8][i] = (_Float16)1.0f;
    VT[sg][9][i] = (_Float16)0.0f;
  }

  const int mrow = (ln < 9) ? ln : 9;   // clamped VT row for PV A-frag
  const float* xb = x + (size_t)b * SEQ * EMB + h * DK;

  // ---- self-compute q fragment from x (half0 lanes; half1 stays 0) ----
  v8h qf = {0, 0, 0, 0, 0, 0, 0, 0};
  if (hf == 0) {
    const float* xq = xb + (size_t)(qb + ln) * EMB;
    const float4 a0 = *(const float4*)(xq);
    const float4 a1 = *(const float4*)(xq + 4);
    float r[8];
    r[0] = __cosf(a0.x + th[0]);
    r[1] = r[0] * __cosf(a0.y + th[1]);
    r[2] = r[1] * __cosf(a0.z + th[2]);
    r[3] = r[2] * __cosf(a0.w + th[3]);
    r[4] = r[3] * __cosf(a1.x + th[4]);
    r[5] = r[4] * __cosf(a1.y + th[5]);
    r[6] = r[5] * __cosf(a1.z + th[6]);
    r[7] = r[6] * __cosf(a1.w + th[7]);
    qf = (v8h){(_Float16)(r[0] * QSCALE), (_Float16)(r[1] * QSCALE),
               (_Float16)(r[2] * QSCALE), (_Float16)(r[3] * QSCALE),
               (_Float16)(r[4] * QSCALE), (_Float16)(r[5] * QSCALE),
               (_Float16)(r[6] * QSCALE), (_Float16)(r[7] * QSCALE)};
  }

  const int cbase = sg * 2;

  v16f acc;
#pragma unroll
  for (int i = 0; i < 16; ++i) acc[i] = 0.f;
  v16f zf;
#pragma unroll
  for (int i = 0; i < 16; ++i) zf[i] = 0.f;

  for (int cg = 0; cg < 2; ++cg) {
    if (cg) __syncthreads();

    // ---- stage own group's chunk: direct x loads (latency hidden by the
    //      32 waves/CU), 16 B/lane Kl writes, VT slot-permuted b16 ----
    {
      const float* xp = xb + (size_t)((cbase + cg) * CHUNK + tg) * EMB;
      const float4 a0 = *(const float4*)(xp);
      const float4 a1 = *(const float4*)(xp + 4);
      const float4 b0 = *(const float4*)(xp + 256 * EMB);
      const float4 b1 = *(const float4*)(xp + 256 * EMB + 4);

      float r0[8], r1[8];
      r0[0] = __cosf(a0.x + th[0]);
      r0[1] = r0[0] * __cosf(a0.y + th[1]);
      r0[2] = r0[1] * __cosf(a0.z + th[2]);
      r0[3] = r0[2] * __cosf(a0.w + th[3]);
      r0[4] = r0[3] * __cosf(a1.x + th[4]);
      r0[5] = r0[4] * __cosf(a1.y + th[5]);
      r0[6] = r0[5] * __cosf(a1.z + th[6]);
      r0[7] = r0[6] * __cosf(a1.w + th[7]);
      r1[0] = __cosf(b0.x + th[0]);
      r1[1] = r1[0] * __cosf(b0.y + th[1]);
      r1[2] = r1[1] * __cosf(b0.z + th[2]);
      r1[3] = r1[2] * __cosf(b0.w + th[3]);
      r1[4] = r1[3] * __cosf(b1.x + th[4]);
      r1[5] = r1[4] * __cosf(b1.y + th[5]);
      r1[6] = r1[5] * __cosf(b1.z + th[6]);
      r1[7] = r1[6] * __cosf(b1.w + th[7]);

      _Float16 h0[8], h1[8];
#pragma unroll
      for (int i = 0; i < 8; ++i) { h0[i] = (_Float16)r0[i]; h1[i] = (_Float16)r1[i]; }

      union { v4h v[2]; float4 f; } u0, u1;
      u0.v[0] = (v4h){h0[0], h0[1], h0[2], h0[3]};
      u0.v[1] = (v4h){h0[4], h0[5], h0[6], h0[7]};
      u1.v[0] = (v4h){h1[0], h1[1], h1[2], h1[3]};
      u1.v[1] = (v4h){h1[4], h1[5], h1[6], h1[7]};
      *(float4*)&Kl[sg][tg * 8]         = u0.f;
      *(float4*)&Kl[sg][(tg + 256) * 8] = u1.f;

      // VT with within-16 slot perm (swap bits 2<->3 of key index)
      const int j0 = tg, j1 = tg + 256;
      const int col0 = (j0 & ~15) | (j0 & 3) | ((j0 & 4) << 1) | ((j0 & 8) >> 1);
      const int col1 = (j1 & ~15) | (j1 & 3) | ((j1 & 4) << 1) | ((j1 & 8) >> 1);
#pragma unroll
      for (int d = 0; d < 8; ++d) {
        VT[sg][d][col0] = h0[d];
        VT[sg][d][col1] = h1[d];
      }
    }
    __syncthreads();

    // ---- compute: 16 32-key blocks (unroll 1: one 16-reg S live at a time;
    //      TLP from 8 waves/SIMD fills the chain holes) ----
#pragma unroll 1
    for (int kb = 0; kb < CHUNK / 32; ++kb) {
      const v8h kf = *(const v8h*)&Kl[sg][(kb * 32 + ln) * 8];
      const v16f s = __builtin_amdgcn_mfma_f32_32x32x16_f16(kf, qf, zf, 0, 0, 0);
      const v8h vt0 = *(const v8h*)&VT[sg][mrow][kb * 32 + hf * 8];
      const v8h vt1 = *(const v8h*)&VT[sg][mrow][kb * 32 + 16 + hf * 8];
      union { v2fp p[4]; v8h v; } p0, p1;
#pragma unroll
      for (int i = 0; i < 4; ++i) {
        p0.p[i] = __builtin_amdgcn_cvt_pkrtz(
            __builtin_amdgcn_exp2f(s[2 * i]),
            __builtin_amdgcn_exp2f(s[2 * i + 1]));
        p1.p[i] = __builtin_amdgcn_cvt_pkrtz(
            __builtin_amdgcn_exp2f(s[8 + 2 * i]),
            __builtin_amdgcn_exp2f(s[8 + 2 * i + 1]));
      }
      acc = __builtin_amdgcn_mfma_f32_32x32x16_f16(vt0, p0.v, acc, 0, 0, 0);
      acc = __builtin_amdgcn_mfma_f32_32x32x16_f16(vt1, p1.v, acc, 0, 0, 0);
    }
  }

  // ---- combine split groups through group-1's dead Kl buffer ----
  // acc: col=q=ln, half0 regs0-3 = dims0-3, reg4 = den; half1 regs0-3 =
  // dims4-7, reg4 = 0 (clamped zeros row).
  __syncthreads();                       // everyone done reading Kl[1]
  float* part = (float*)&Kl[1][0];       // 2048 floats >= 4*2*32*5
  if (sg == 1) {
    float* p = part + (((wl * 2 + hf) * 32) + ln) * 5;
    p[0] = acc[0]; p[1] = acc[1]; p[2] = acc[2]; p[3] = acc[3]; p[4] = acc[4];
  }
  __syncthreads();
  if (sg == 0) {
    const float* p = part + (((wl * 2 + hf) * 32) + ln) * 5;
    acc[0] += p[0]; acc[1] += p[1]; acc[2] += p[2]; acc[3] += p[3];
    acc[4] += p[4];
    const float den = __shfl(acc[4], ln, 64);   // from half0 lane ln
    const float inv = 1.0f / den;
    const int qrow = qb + ln;
    v4h o = {(_Float16)(acc[0] * inv), (_Float16)(acc[1] * inv),
             (_Float16)(acc[2] * inv), (_Float16)(acc[3] * inv)};
    *(v4h*)(Ah + ((size_t)b * SEQ + qrow) * EMB + h * DK + hf * 4) = o;
  }
}

// ---------------------------------------------------------------------------
// MFMA projection (unchanged from R10-R17). out = Ah · W^T, fp32 out.
// W converted f32->f16 during LDS staging; W row-major IS the B-fragment
// source. Block: 64 rows x 64 cols (grid 128x2), LDS 35 KB, 4 blocks/CU.
// ---------------------------------------------------------------------------
__launch_bounds__(256, 4)
__global__ void proj_kernel(const _Float16* __restrict__ Ah,
                            const float* __restrict__ W,
                            float* __restrict__ out) {
  __shared__ __align__(16) _Float16 Ahs[64][136];
  __shared__ __align__(16) _Float16 Whs[64][136];

  const int tid  = threadIdx.x;
  const int L    = tid & 63;
  const int wv   = tid >> 6;
  const int quad = L >> 4;
  const int ln   = L & 15;
  const int rowbase = blockIdx.x * 64;
  const int colbase = blockIdx.y * 64;

#pragma unroll
  for (int it = 0; it < 4; ++it) {
    const int idx = it * 256 + tid;
    const int r  = idx >> 4;
    const int c8 = idx & 15;
    *(uint4*)&Ahs[r][c8 * 8] =
        *(const uint4*)(Ah + (size_t)(rowbase + r) * EMB + c8 * 8);
  }
#pragma unroll
  for (int it = 0; it < 8; ++it) {
    const int idx = it * 256 + tid;
    const int n  = idx >> 5;
    const int c4 = idx & 31;
    const float4 w = *(const float4*)(W + (size_t)(colbase + n) * EMB + c4 * 4);
    v4h wh = {(_Float16)w.x, (_Float16)w.y, (_Float16)w.z, (_Float16)w.w};
    *(v4h*)&Whs[n][c4 * 4] = wh;
  }
  __syncthreads();

  v4f acc[4];
#pragma unroll
  for (int nt = 0; nt < 4; ++nt) acc[nt] = (v4f){0.f, 0.f, 0.f, 0.f};

#pragma unroll
  for (int k8 = 0; k8 < 8; ++k8) {
    const v4h af = *(const v4h*)&Ahs[wv * 16 + ln][k8 * 16 + quad * 4];
#pragma unroll
    for (int nt = 0; nt < 4; ++nt) {
      const v4h bf = *(const v4h*)&Whs[nt * 16 + ln][k8 * 16 + quad * 4];
      acc[nt] = __builtin_amdgcn_mfma_f32_16x16x16f16(af, bf, acc[nt], 0, 0, 0);
    }
  }

#pragma unroll
  for (int nt = 0; nt < 4; ++nt) {
    const int col = colbase + nt * 16 + ln;
#pragma unroll
    for (int r = 0; r < 4; ++r) {
      out[(size_t)(rowbase + wv * 16 + quad * 4 + r) * EMB + col] = acc[nt][r];
    }
  }
}

// ---------------------------------------------------------------------------
extern "C" void kernel_launch(void* const* d_in, const int* in_sizes, int n_in,
                              void* d_out, int out_size, void* d_ws, size_t ws_size,
                              hipStream_t stream) {
  const float* x     = (const float*)d_in[0];  // [4,2048,128]
  const float* theta = (const float*)d_in[1];  // [8]
  const float* w_out = (const float*)d_in[2];  // [128,128]
  float* out = (float*)d_out;                  // [4,2048,128]

  _Float16* Ah = (_Float16*)d_ws;              // [8192][128] f16 = 2 MB

  // fused features + attention: 64 bh x 16 q-chunks = 1024 blocks, 8 waves
  attn_kernel<<<dim3(1024), dim3(512), 0, stream>>>(x, theta, Ah);

  // projection: 128 row-tiles x 2 col-tiles
  proj_kernel<<<dim3((BATCH * SEQ) / 64, 2), dim3(256), 0, stream>>>(Ah, w_out, out);
}